// Round 1
// baseline (986.695 us; speedup 1.0000x reference)
//
#include <hip/hip_runtime.h>
#include <stdint.h>

typedef unsigned int uint;
typedef unsigned short ushort;

#define NPTS  262144
#define PLANE_T_ELEMS (65536 * 32)
#define WS_PLANES_BYTES ((size_t)3 * PLANE_T_ELEMS * 2)
#define WS_GT_OFF  WS_PLANES_BYTES
#define WS_NEEDED  (WS_PLANES_BYTES + (size_t)32768 * 4)

__device__ __forceinline__ ushort f2bf(float f) {
  union { float f; uint u; } v; v.f = f;
  uint r = v.u + 0x7fffu + ((v.u >> 16) & 1u);   // round-to-nearest-even
  return (ushort)(r >> 16);
}
__device__ __forceinline__ float bf_lo(uint u) {
  union { uint u; float f; } v; v.u = u << 16; return v.f;
}
__device__ __forceinline__ float bf_hi(uint u) {
  union { uint u; float f; } v; v.u = u & 0xffff0000u; return v.f;
}

// (C,H,W) fp32 -> (H,W,C) bf16, C=32 contiguous per texel (64B)
__global__ __launch_bounds__(256) void transpose_planes_k(
    const float* __restrict__ pxy, const float* __restrict__ pyz,
    const float* __restrict__ pxz, ushort* __restrict__ out) {
  int plane = blockIdx.x >> 8;
  int h = blockIdx.x & 255;
  const float* src = (plane == 0) ? pxy : (plane == 1) ? pyz : pxz;
  int w = threadIdx.x;
  int p = (h << 8) + w;
  uint vals[16];
#pragma unroll
  for (int c = 0; c < 32; c += 2) {
    float f0 = src[(size_t)c * 65536 + p];       // coalesced across lanes
    float f1 = src[(size_t)(c + 1) * 65536 + p];
    vals[c >> 1] = (uint)f2bf(f0) | ((uint)f2bf(f1) << 16);
  }
  uint4* d4 = (uint4*)(out + (size_t)plane * PLANE_T_ELEMS + (size_t)p * 32);
#pragma unroll
  for (int i = 0; i < 4; ++i)
    d4[i] = make_uint4(vals[4 * i], vals[4 * i + 1], vals[4 * i + 2], vals[4 * i + 3]);
}

// G[x][y][z] fp32 -> Gt[y][z][x] fp32 (x contiguous for the inner dot with xy[])
__global__ __launch_bounds__(256) void transpose_g_k(const float* __restrict__ g,
                                                     float* __restrict__ gt) {
  int t = blockIdx.x * 256 + threadIdx.x;  // t = y*1024 + z*32 + x
  int x = t & 31;
  int z = (t >> 5) & 31;
  int y = t >> 10;
  gt[t] = g[x * 1024 + y * 32 + z];
}

// torch grid_sample: bilinear, zeros padding, align_corners=True, 256x256, C=32
template <bool BIG, class F>
__device__ __forceinline__ void sample_plane(const ushort* __restrict__ bt,
                                             const float* __restrict__ bf,
                                             float gw, float gh, F store) {
  float fx = (gw + 1.0f) * 0.5f * 255.0f;
  float fy = (gh + 1.0f) * 0.5f * 255.0f;
  float fx0 = floorf(fx), fy0 = floorf(fy);
  float wx1 = fx - fx0, wy1 = fy - fy0;
  float wx0 = 1.0f - wx1, wy0 = 1.0f - wy1;
  int ix0 = (int)fx0, iy0 = (int)fy0;
  int ix1 = ix0 + 1, iy1 = iy0 + 1;
  bool vx0 = (ix0 >= 0) & (ix0 < 256);
  bool vx1 = (ix1 >= 0) & (ix1 < 256);
  bool vy0 = (iy0 >= 0) & (iy0 < 256);
  bool vy1 = (iy1 >= 0) & (iy1 < 256);
  float w00 = (vx0 & vy0) ? wx0 * wy0 : 0.0f;
  float w10 = (vx1 & vy0) ? wx1 * wy0 : 0.0f;
  float w01 = (vx0 & vy1) ? wx0 * wy1 : 0.0f;
  float w11 = (vx1 & vy1) ? wx1 * wy1 : 0.0f;
  int cx0 = min(max(ix0, 0), 255), cx1 = min(max(ix1, 0), 255);
  int cy0 = min(max(iy0, 0), 255), cy1 = min(max(iy1, 0), 255);
  if (BIG) {
    const ushort* t00 = bt + (size_t)(((cy0 << 8) + cx0) * 32);
    const ushort* t10 = bt + (size_t)(((cy0 << 8) + cx1) * 32);
    const ushort* t01 = bt + (size_t)(((cy1 << 8) + cx0) * 32);
    const ushort* t11 = bt + (size_t)(((cy1 << 8) + cx1) * 32);
#pragma unroll
    for (int cc = 0; cc < 32; cc += 8) {
      uint4 a = *(const uint4*)(t00 + cc);
      uint4 b = *(const uint4*)(t10 + cc);
      uint4 c = *(const uint4*)(t01 + cc);
      uint4 d = *(const uint4*)(t11 + cc);
      const uint* pa = (const uint*)&a; const uint* pb = (const uint*)&b;
      const uint* pc = (const uint*)&c; const uint* pd = (const uint*)&d;
#pragma unroll
      for (int j = 0; j < 4; ++j) {
        float v0 = w00 * bf_lo(pa[j]) + w10 * bf_lo(pb[j]) +
                   w01 * bf_lo(pc[j]) + w11 * bf_lo(pd[j]);
        float v1 = w00 * bf_hi(pa[j]) + w10 * bf_hi(pb[j]) +
                   w01 * bf_hi(pc[j]) + w11 * bf_hi(pd[j]);
        store(cc + 2 * j, v0);
        store(cc + 2 * j + 1, v1);
      }
    }
  } else {
    int o00 = (cy0 << 8) + cx0, o10 = (cy0 << 8) + cx1;
    int o01 = (cy1 << 8) + cx0, o11 = (cy1 << 8) + cx1;
#pragma unroll
    for (int c = 0; c < 32; ++c) {
      const float* base = bf + (size_t)c * 65536;
      float v = w00 * base[o00] + w10 * base[o10] + w01 * base[o01] + w11 * base[o11];
      store(c, v);
    }
  }
}

template <bool BIG>
__global__ __launch_bounds__(256) void tucker_main_k(
    const float* __restrict__ coords,
    const float* __restrict__ pxy, const float* __restrict__ pyz,
    const float* __restrict__ pxz, const float* __restrict__ g,
    const ushort* __restrict__ planes_t, const float* __restrict__ gt,
    float* __restrict__ out) {
  __shared__ float s_yz[256 * 33];   // padded: bank = (tid+y)%32, conflict-free
  int tid = threadIdx.x;
  int p = blockIdx.x * 256 + tid;
  float c0 = coords[3 * p + 0] / 1.3f;
  float c1 = coords[3 * p + 1] / 1.3f;
  float c2 = coords[3 * p + 2] / 1.3f;

  float xy[32], xz[32];              // static-indexed only -> VGPRs
  float* yzrow = &s_yz[tid * 33];

  // xy-plane: W<-x(c0), H<-y(c1); yz-plane: W<-y(c1), H<-z(c2); xz: W<-x(c0), H<-z(c2)
  sample_plane<BIG>(planes_t, pxy, c0, c1,
                    [&](int c, float v) { xy[c] = v; });
  sample_plane<BIG>(planes_t + (size_t)1 * PLANE_T_ELEMS, pyz, c1, c2,
                    [&](int c, float v) { yzrow[c] = v; });
  sample_plane<BIG>(planes_t + (size_t)2 * PLANE_T_ELEMS, pxz, c0, c2,
                    [&](int c, float v) { xz[c] = v; });

  // out = sum_y yz[y] * sum_z xz[z] * sum_x Gt[y][z][x]*xy[x]
  float acc = 0.0f;
  for (int y = 0; y < 32; ++y) {
    float yzv = yzrow[y];
    float accy = 0.0f;
    if (BIG) {
      const float4* grow = (const float4*)gt + y * 256;  // uniform -> s_load
#pragma unroll
      for (int z = 0; z < 32; ++z) {
        const float4* r = grow + z * 8;
        float t0 = 0.f, t1 = 0.f, t2 = 0.f, t3 = 0.f;
#pragma unroll
        for (int q = 0; q < 8; ++q) {
          float4 gv = r[q];
          t0 = fmaf(gv.x, xy[4 * q + 0], t0);
          t1 = fmaf(gv.y, xy[4 * q + 1], t1);
          t2 = fmaf(gv.z, xy[4 * q + 2], t2);
          t3 = fmaf(gv.w, xy[4 * q + 3], t3);
        }
        accy = fmaf((t0 + t1) + (t2 + t3), xz[z], accy);
      }
    } else {
#pragma unroll
      for (int z = 0; z < 32; ++z) {
        float t0 = 0.f, t1 = 0.f, t2 = 0.f, t3 = 0.f;
#pragma unroll
        for (int x = 0; x < 32; x += 4) {
          t0 = fmaf(g[(x + 0) * 1024 + y * 32 + z], xy[x + 0], t0);
          t1 = fmaf(g[(x + 1) * 1024 + y * 32 + z], xy[x + 1], t1);
          t2 = fmaf(g[(x + 2) * 1024 + y * 32 + z], xy[x + 2], t2);
          t3 = fmaf(g[(x + 3) * 1024 + y * 32 + z], xy[x + 3], t3);
        }
        accy = fmaf((t0 + t1) + (t2 + t3), xz[z], accy);
      }
    }
    acc = fmaf(accy, yzv, acc);
  }
  out[p] = acc;
}

extern "C" void kernel_launch(void* const* d_in, const int* in_sizes, int n_in,
                              void* d_out, int out_size, void* d_ws, size_t ws_size,
                              hipStream_t stream) {
  const float* coords = (const float*)d_in[0];
  const float* pxy = (const float*)d_in[1];
  const float* pyz = (const float*)d_in[2];
  const float* pxz = (const float*)d_in[3];
  const float* g   = (const float*)d_in[4];
  float* out = (float*)d_out;

  if (ws_size >= WS_NEEDED) {
    ushort* planes_t = (ushort*)d_ws;
    float* gt = (float*)((char*)d_ws + WS_GT_OFF);
    hipLaunchKernelGGL(transpose_planes_k, dim3(768), dim3(256), 0, stream,
                       pxy, pyz, pxz, planes_t);
    hipLaunchKernelGGL(transpose_g_k, dim3(128), dim3(256), 0, stream, g, gt);
    hipLaunchKernelGGL((tucker_main_k<true>), dim3(NPTS / 256), dim3(256), 0, stream,
                       coords, pxy, pyz, pxz, g, planes_t, gt, out);
  } else {
    hipLaunchKernelGGL((tucker_main_k<false>), dim3(NPTS / 256), dim3(256), 0, stream,
                       coords, pxy, pyz, pxz, g, nullptr, nullptr, out);
  }
}

// Round 2
// 87.149 us; speedup vs baseline: 11.3219x; 11.3219x over previous
//
#include <hip/hip_runtime.h>
#include <stdint.h>

typedef unsigned int uint;
typedef unsigned short ushort;

#define NPTS  262144
#define PLANE_T_ELEMS (65536 * 32)
#define WS_PLANES_BYTES ((size_t)3 * PLANE_T_ELEMS * 2)   // 12582912
#define WS_GRB_OFF  WS_PLANES_BYTES
#define WS_NEEDED   (WS_PLANES_BYTES + (size_t)32768 * 2)

typedef __attribute__((ext_vector_type(8))) short bf16x8;   // 8 bf16 = 4 VGPR
typedef __attribute__((ext_vector_type(4))) float f32x4;

__device__ __forceinline__ ushort f2bf(float f) {
  union { float f; uint u; } v; v.f = f;
  uint r = v.u + 0x7fffu + ((v.u >> 16) & 1u);   // RNE
  return (ushort)(r >> 16);
}
__device__ __forceinline__ float bf_lo(uint u) {
  union { uint u; float f; } v; v.u = u << 16; return v.f;
}
__device__ __forceinline__ float bf_hi(uint u) {
  union { uint u; float f; } v; v.u = u & 0xffff0000u; return v.f;
}
__device__ __forceinline__ float b2f(ushort u) {
  union { uint u; float f; } v; v.u = (uint)u << 16; return v.f;
}
__device__ __forceinline__ uint cvtpk_bf16(float lo, float hi) {
  uint r;
  asm("v_cvt_pk_bf16_f32 %0, %1, %2" : "=v"(r) : "v"(lo), "v"(hi));
  return r;
}

// ---------- prep kernels ----------

// (C,H,W) fp32 -> (H,W,C) bf16, C=32 contiguous per texel (64B)
__global__ __launch_bounds__(256) void transpose_planes_k(
    const float* __restrict__ pxy, const float* __restrict__ pyz,
    const float* __restrict__ pxz, ushort* __restrict__ out) {
  int plane = blockIdx.x >> 8;
  int h = blockIdx.x & 255;
  const float* src = (plane == 0) ? pxy : (plane == 1) ? pyz : pxz;
  int w = threadIdx.x;
  int p = (h << 8) + w;
  uint vals[16];
#pragma unroll
  for (int c = 0; c < 32; c += 2) {
    float f0 = src[(size_t)c * 65536 + p];
    float f1 = src[(size_t)(c + 1) * 65536 + p];
    vals[c >> 1] = (uint)f2bf(f0) | ((uint)f2bf(f1) << 16);
  }
  uint4* d4 = (uint4*)(out + (size_t)plane * PLANE_T_ELEMS + (size_t)p * 32);
#pragma unroll
  for (int i = 0; i < 4; ++i)
    d4[i] = make_uint4(vals[4 * i], vals[4 * i + 1], vals[4 * i + 2], vals[4 * i + 3]);
}

// G[x][y][z] -> B-fragment-ordered bf16 table:
// e = ((y*2+xh)*64 + l)*8 + j  ->  G[x= xh*16+(l&15)][y][z= (l>>4)*8+j]
__global__ __launch_bounds__(256) void prep_grb_k(const float* __restrict__ g,
                                                  ushort* __restrict__ grb) {
  int e = blockIdx.x * 256 + threadIdx.x;   // 0..32767
  int j = e & 7;
  int l = (e >> 3) & 63;
  int xh = (e >> 9) & 1;
  int y = e >> 10;
  int x = xh * 16 + (l & 15);
  int z = ((l >> 4) << 3) + j;
  grb[e] = f2bf(g[x * 1024 + y * 32 + z]);
}

// ---------- bilinear sampler (validated in R1) ----------
template <bool BIG, class F>
__device__ __forceinline__ void sample_plane(const ushort* __restrict__ bt,
                                             const float* __restrict__ bf,
                                             float gw, float gh, F store) {
  float fx = (gw + 1.0f) * 0.5f * 255.0f;
  float fy = (gh + 1.0f) * 0.5f * 255.0f;
  float fx0 = floorf(fx), fy0 = floorf(fy);
  float wx1 = fx - fx0, wy1 = fy - fy0;
  float wx0 = 1.0f - wx1, wy0 = 1.0f - wy1;
  int ix0 = (int)fx0, iy0 = (int)fy0;
  int ix1 = ix0 + 1, iy1 = iy0 + 1;
  bool vx0 = (ix0 >= 0) & (ix0 < 256);
  bool vx1 = (ix1 >= 0) & (ix1 < 256);
  bool vy0 = (iy0 >= 0) & (iy0 < 256);
  bool vy1 = (iy1 >= 0) & (iy1 < 256);
  float w00 = (vx0 & vy0) ? wx0 * wy0 : 0.0f;
  float w10 = (vx1 & vy0) ? wx1 * wy0 : 0.0f;
  float w01 = (vx0 & vy1) ? wx0 * wy1 : 0.0f;
  float w11 = (vx1 & vy1) ? wx1 * wy1 : 0.0f;
  int cx0 = min(max(ix0, 0), 255), cx1 = min(max(ix1, 0), 255);
  int cy0 = min(max(iy0, 0), 255), cy1 = min(max(iy1, 0), 255);
  if (BIG) {
    const ushort* t00 = bt + (size_t)(((cy0 << 8) + cx0) * 32);
    const ushort* t10 = bt + (size_t)(((cy0 << 8) + cx1) * 32);
    const ushort* t01 = bt + (size_t)(((cy1 << 8) + cx0) * 32);
    const ushort* t11 = bt + (size_t)(((cy1 << 8) + cx1) * 32);
#pragma unroll
    for (int cc = 0; cc < 32; cc += 8) {
      uint4 a = *(const uint4*)(t00 + cc);
      uint4 b = *(const uint4*)(t10 + cc);
      uint4 c = *(const uint4*)(t01 + cc);
      uint4 d = *(const uint4*)(t11 + cc);
      const uint* pa = (const uint*)&a; const uint* pb = (const uint*)&b;
      const uint* pc = (const uint*)&c; const uint* pd = (const uint*)&d;
#pragma unroll
      for (int j = 0; j < 4; ++j) {
        float v0 = w00 * bf_lo(pa[j]) + w10 * bf_lo(pb[j]) +
                   w01 * bf_lo(pc[j]) + w11 * bf_lo(pd[j]);
        float v1 = w00 * bf_hi(pa[j]) + w10 * bf_hi(pb[j]) +
                   w01 * bf_hi(pc[j]) + w11 * bf_hi(pd[j]);
        store(cc + 2 * j, v0);
        store(cc + 2 * j + 1, v1);
      }
    }
  } else {
    int o00 = (cy0 << 8) + cx0, o10 = (cy0 << 8) + cx1;
    int o01 = (cy1 << 8) + cx0, o11 = (cy1 << 8) + cx1;
#pragma unroll
    for (int c = 0; c < 32; ++c) {
      const float* base = bf + (size_t)c * 65536;
      float v = w00 * base[o00] + w10 * base[o10] + w01 * base[o01] + w11 * base[o11];
      store(c, v);
    }
  }
}

// ---------- MFMA main kernel ----------
__global__ __launch_bounds__(256) void tucker_mfma_k(
    const float* __restrict__ coords,
    const ushort* __restrict__ planes_t,
    const ushort* __restrict__ grb,
    float* __restrict__ out) {
  __shared__ __align__(16) ushort xy_s[256][32];
  __shared__ __align__(16) ushort yz_s[256][32];
  __shared__ __align__(16) ushort xz_s[256][32];

  int tid = threadIdx.x;
  int p = blockIdx.x * 256 + tid;
  float c0c = coords[3 * p + 0] * (1.0f / 1.3f);
  float c1c = coords[3 * p + 1] * (1.0f / 1.3f);
  float c2c = coords[3 * p + 2] * (1.0f / 1.3f);

  // sample own point -> packed bf16 rows in LDS
  {
    uint buf[16];
    auto pack = [&](int c, float v) {
      ushort h = f2bf(v);
      if (c & 1) buf[c >> 1] |= ((uint)h << 16);
      else buf[c >> 1] = (uint)h;
    };
    sample_plane<true>(planes_t, nullptr, c0c, c1c, pack);
    uint4* r = (uint4*)xy_s[tid];
#pragma unroll
    for (int i = 0; i < 4; ++i)
      r[i] = make_uint4(buf[4*i], buf[4*i+1], buf[4*i+2], buf[4*i+3]);
    sample_plane<true>(planes_t + (size_t)PLANE_T_ELEMS, nullptr, c1c, c2c, pack);
    r = (uint4*)yz_s[tid];
#pragma unroll
    for (int i = 0; i < 4; ++i)
      r[i] = make_uint4(buf[4*i], buf[4*i+1], buf[4*i+2], buf[4*i+3]);
    sample_plane<true>(planes_t + (size_t)2 * PLANE_T_ELEMS, nullptr, c0c, c2c, pack);
    r = (uint4*)xz_s[tid];
#pragma unroll
    for (int i = 0; i < 4; ++i)
      r[i] = make_uint4(buf[4*i], buf[4*i+1], buf[4*i+2], buf[4*i+3]);
  }
  __syncthreads();

  int l = tid & 63;        // lane
  int wv = tid >> 6;       // wave in block
  int s = l & 15;          // point-in-tile (A row, C col)
  int kb = l >> 4;         // k-block 0..3
  const ushort* gl = grb + (size_t)l * 8;   // lane's B-frag base

#pragma unroll
  for (int t = 0; t < 4; ++t) {
    int pb = wv * 64 + t * 16 + s;          // this lane's point (A side)
    // preload yz row (32 bf16 = 16 packed uints)
    const uint4* yr = (const uint4*)yz_s[pb];
    uint4 q0 = yr[0], q1 = yr[1], q2 = yr[2], q3 = yr[3];
    uint yzp[16] = {q0.x, q0.y, q0.z, q0.w, q1.x, q1.y, q1.z, q1.w,
                    q2.x, q2.y, q2.z, q2.w, q3.x, q3.y, q3.z, q3.w};
    // preload this lane's 8 xz values (z = kb*8 + j)
    uint4 xzu = ((const uint4*)xz_s[pb])[kb];
    float xzf[8] = {bf_lo(xzu.x), bf_hi(xzu.x), bf_lo(xzu.y), bf_hi(xzu.y),
                    bf_lo(xzu.z), bf_hi(xzu.z), bf_lo(xzu.w), bf_hi(xzu.w)};

    f32x4 acc0 = {0.f, 0.f, 0.f, 0.f};
    f32x4 acc1 = {0.f, 0.f, 0.f, 0.f};
#pragma unroll
    for (int y = 0; y < 32; ++y) {
      float yv = (y & 1) ? bf_hi(yzp[y >> 1]) : bf_lo(yzp[y >> 1]);
      union { uint u[4]; bf16x8 v; } a;
      a.u[0] = cvtpk_bf16(yv * xzf[0], yv * xzf[1]);
      a.u[1] = cvtpk_bf16(yv * xzf[2], yv * xzf[3]);
      a.u[2] = cvtpk_bf16(yv * xzf[4], yv * xzf[5]);
      a.u[3] = cvtpk_bf16(yv * xzf[6], yv * xzf[7]);
      bf16x8 b0 = *(const bf16x8*)(gl + y * 1024);
      bf16x8 b1 = *(const bf16x8*)(gl + y * 1024 + 512);
      acc0 = __builtin_amdgcn_mfma_f32_16x16x32_bf16(a.v, b0, acc0, 0, 0, 0);
      acc1 = __builtin_amdgcn_mfma_f32_16x16x32_bf16(a.v, b1, acc1, 0, 0, 0);
    }

    // epilogue: out[m] = sum_x xy[m][x] * W[m][x]
    int gp0 = blockIdx.x * 256 + wv * 64 + t * 16;
#pragma unroll
    for (int r = 0; r < 4; ++r) {
      int m = kb * 4 + r;                   // C row
      int pm = wv * 64 + t * 16 + m;
      float v = acc0[r] * b2f(xy_s[pm][s]) + acc1[r] * b2f(xy_s[pm][16 + s]);
      v += __shfl_xor(v, 1, 64);
      v += __shfl_xor(v, 2, 64);
      v += __shfl_xor(v, 4, 64);
      v += __shfl_xor(v, 8, 64);
      if (s == 0) out[gp0 + m] = v;
    }
  }
}

// ---------- fallback (no workspace): R1 slow-but-correct path ----------
__global__ __launch_bounds__(256) void tucker_small_k(
    const float* __restrict__ coords,
    const float* __restrict__ pxy, const float* __restrict__ pyz,
    const float* __restrict__ pxz, const float* __restrict__ g,
    float* __restrict__ out) {
  __shared__ float s_yz[256 * 33];
  int tid = threadIdx.x;
  int p = blockIdx.x * 256 + tid;
  float c0 = coords[3 * p + 0] / 1.3f;
  float c1 = coords[3 * p + 1] / 1.3f;
  float c2 = coords[3 * p + 2] / 1.3f;
  float xy[32], xz[32];
  float* yzrow = &s_yz[tid * 33];
  sample_plane<false>(nullptr, pxy, c0, c1, [&](int c, float v) { xy[c] = v; });
  sample_plane<false>(nullptr, pyz, c1, c2, [&](int c, float v) { yzrow[c] = v; });
  sample_plane<false>(nullptr, pxz, c0, c2, [&](int c, float v) { xz[c] = v; });
  float acc = 0.0f;
  for (int y = 0; y < 32; ++y) {
    float yzv = yzrow[y];
    float accy = 0.0f;
#pragma unroll
    for (int z = 0; z < 32; ++z) {
      float t0 = 0.f, t1 = 0.f, t2 = 0.f, t3 = 0.f;
#pragma unroll
      for (int x = 0; x < 32; x += 4) {
        t0 = fmaf(g[(x + 0) * 1024 + y * 32 + z], xy[x + 0], t0);
        t1 = fmaf(g[(x + 1) * 1024 + y * 32 + z], xy[x + 1], t1);
        t2 = fmaf(g[(x + 2) * 1024 + y * 32 + z], xy[x + 2], t2);
        t3 = fmaf(g[(x + 3) * 1024 + y * 32 + z], xy[x + 3], t3);
      }
      accy = fmaf((t0 + t1) + (t2 + t3), xz[z], accy);
    }
    acc = fmaf(accy, yzv, acc);
  }
  out[p] = acc;
}

extern "C" void kernel_launch(void* const* d_in, const int* in_sizes, int n_in,
                              void* d_out, int out_size, void* d_ws, size_t ws_size,
                              hipStream_t stream) {
  const float* coords = (const float*)d_in[0];
  const float* pxy = (const float*)d_in[1];
  const float* pyz = (const float*)d_in[2];
  const float* pxz = (const float*)d_in[3];
  const float* g   = (const float*)d_in[4];
  float* out = (float*)d_out;

  if (ws_size >= WS_NEEDED) {
    ushort* planes_t = (ushort*)d_ws;
    ushort* grb = (ushort*)((char*)d_ws + WS_GRB_OFF);
    hipLaunchKernelGGL(transpose_planes_k, dim3(768), dim3(256), 0, stream,
                       pxy, pyz, pxz, planes_t);
    hipLaunchKernelGGL(prep_grb_k, dim3(128), dim3(256), 0, stream, g, grb);
    hipLaunchKernelGGL(tucker_mfma_k, dim3(NPTS / 256), dim3(256), 0, stream,
                       coords, planes_t, grb, out);
  } else {
    hipLaunchKernelGGL(tucker_small_k, dim3(NPTS / 256), dim3(256), 0, stream,
                       coords, pxy, pyz, pxz, g, out);
  }
}

// Round 3
// 68.875 us; speedup vs baseline: 14.3259x; 1.2653x over previous
//
#include <hip/hip_runtime.h>
#include <stdint.h>

typedef unsigned int uint;
typedef unsigned short ushort;

#define NPTS  262144
#define PLANE_T_ELEMS (65536 * 32)
#define WS_PLANES_BYTES ((size_t)3 * PLANE_T_ELEMS * 2)   // 12582912
#define WS_GRB_OFF  WS_PLANES_BYTES
#define WS_NEEDED   (WS_PLANES_BYTES + (size_t)32768 * 2)

typedef __attribute__((ext_vector_type(8))) short bf16x8;   // 8 bf16 = 4 VGPR
typedef __attribute__((ext_vector_type(4))) float f32x4;

__device__ __forceinline__ ushort f2bf(float f) {
  union { float f; uint u; } v; v.f = f;
  uint r = v.u + 0x7fffu + ((v.u >> 16) & 1u);   // RNE
  return (ushort)(r >> 16);
}
__device__ __forceinline__ float bf_lo(uint u) {
  union { uint u; float f; } v; v.u = u << 16; return v.f;
}
__device__ __forceinline__ float bf_hi(uint u) {
  union { uint u; float f; } v; v.u = u & 0xffff0000u; return v.f;
}
__device__ __forceinline__ float b2f(ushort u) {
  union { uint u; float f; } v; v.u = (uint)u << 16; return v.f;
}
__device__ __forceinline__ uint cvtpk_bf16(float lo, float hi) {
  uint r;
  asm("v_cvt_pk_bf16_f32 %0, %1, %2" : "=v"(r) : "v"(lo), "v"(hi));
  return r;
}

// ---------- prep kernels (unchanged, verified) ----------

// (C,H,W) fp32 -> (H,W,C) bf16, C=32 contiguous per texel (64B)
__global__ __launch_bounds__(256) void transpose_planes_k(
    const float* __restrict__ pxy, const float* __restrict__ pyz,
    const float* __restrict__ pxz, ushort* __restrict__ out) {
  int plane = blockIdx.x >> 8;
  int h = blockIdx.x & 255;
  const float* src = (plane == 0) ? pxy : (plane == 1) ? pyz : pxz;
  int w = threadIdx.x;
  int p = (h << 8) + w;
  uint vals[16];
#pragma unroll
  for (int c = 0; c < 32; c += 2) {
    float f0 = src[(size_t)c * 65536 + p];
    float f1 = src[(size_t)(c + 1) * 65536 + p];
    vals[c >> 1] = (uint)f2bf(f0) | ((uint)f2bf(f1) << 16);
  }
  uint4* d4 = (uint4*)(out + (size_t)plane * PLANE_T_ELEMS + (size_t)p * 32);
#pragma unroll
  for (int i = 0; i < 4; ++i)
    d4[i] = make_uint4(vals[4 * i], vals[4 * i + 1], vals[4 * i + 2], vals[4 * i + 3]);
}

// G[x][y][z] -> B-fragment-ordered bf16 table:
// e = ((y*2+xh)*64 + l)*8 + j  ->  G[x= xh*16+(l&15)][y][z= (l>>4)*8+j]
__global__ __launch_bounds__(256) void prep_grb_k(const float* __restrict__ g,
                                                  ushort* __restrict__ grb) {
  int e = blockIdx.x * 256 + threadIdx.x;   // 0..32767
  int j = e & 7;
  int l = (e >> 3) & 63;
  int xh = (e >> 9) & 1;
  int y = e >> 10;
  int x = xh * 16 + (l & 15);
  int z = ((l >> 4) << 3) + j;
  grb[e] = f2bf(g[x * 1024 + y * 32 + z]);
}

// ---------- bilinear sampler (verified) ----------
template <bool BIG, class F>
__device__ __forceinline__ void sample_plane(const ushort* __restrict__ bt,
                                             const float* __restrict__ bf,
                                             float gw, float gh, F store) {
  float fx = (gw + 1.0f) * 0.5f * 255.0f;
  float fy = (gh + 1.0f) * 0.5f * 255.0f;
  float fx0 = floorf(fx), fy0 = floorf(fy);
  float wx1 = fx - fx0, wy1 = fy - fy0;
  float wx0 = 1.0f - wx1, wy0 = 1.0f - wy1;
  int ix0 = (int)fx0, iy0 = (int)fy0;
  int ix1 = ix0 + 1, iy1 = iy0 + 1;
  bool vx0 = (ix0 >= 0) & (ix0 < 256);
  bool vx1 = (ix1 >= 0) & (ix1 < 256);
  bool vy0 = (iy0 >= 0) & (iy0 < 256);
  bool vy1 = (iy1 >= 0) & (iy1 < 256);
  float w00 = (vx0 & vy0) ? wx0 * wy0 : 0.0f;
  float w10 = (vx1 & vy0) ? wx1 * wy0 : 0.0f;
  float w01 = (vx0 & vy1) ? wx0 * wy1 : 0.0f;
  float w11 = (vx1 & vy1) ? wx1 * wy1 : 0.0f;
  int cx0 = min(max(ix0, 0), 255), cx1 = min(max(ix1, 0), 255);
  int cy0 = min(max(iy0, 0), 255), cy1 = min(max(iy1, 0), 255);
  if (BIG) {
    const ushort* t00 = bt + (size_t)(((cy0 << 8) + cx0) * 32);
    const ushort* t10 = bt + (size_t)(((cy0 << 8) + cx1) * 32);
    const ushort* t01 = bt + (size_t)(((cy1 << 8) + cx0) * 32);
    const ushort* t11 = bt + (size_t)(((cy1 << 8) + cx1) * 32);
#pragma unroll
    for (int cc = 0; cc < 32; cc += 8) {
      uint4 a = *(const uint4*)(t00 + cc);
      uint4 b = *(const uint4*)(t10 + cc);
      uint4 c = *(const uint4*)(t01 + cc);
      uint4 d = *(const uint4*)(t11 + cc);
      const uint* pa = (const uint*)&a; const uint* pb = (const uint*)&b;
      const uint* pc = (const uint*)&c; const uint* pd = (const uint*)&d;
#pragma unroll
      for (int j = 0; j < 4; ++j) {
        float v0 = w00 * bf_lo(pa[j]) + w10 * bf_lo(pb[j]) +
                   w01 * bf_lo(pc[j]) + w11 * bf_lo(pd[j]);
        float v1 = w00 * bf_hi(pa[j]) + w10 * bf_hi(pb[j]) +
                   w01 * bf_hi(pc[j]) + w11 * bf_hi(pd[j]);
        store(cc + 2 * j, v0);
        store(cc + 2 * j + 1, v1);
      }
    }
  } else {
    int o00 = (cy0 << 8) + cx0, o10 = (cy0 << 8) + cx1;
    int o01 = (cy1 << 8) + cx0, o11 = (cy1 << 8) + cx1;
#pragma unroll
    for (int c = 0; c < 32; ++c) {
      const float* base = bf + (size_t)c * 65536;
      float v = w00 * base[o00] + w10 * base[o10] + w01 * base[o01] + w11 * base[o11];
      store(c, v);
    }
  }
}

// ---------- MFMA main kernel: 1 wave per block, y-outer B-reuse ----------
__global__ __launch_bounds__(64) void tucker_mfma_k(
    const float* __restrict__ coords,
    const ushort* __restrict__ planes_t,
    const ushort* __restrict__ grb,
    float* __restrict__ out) {
  __shared__ __align__(16) ushort xy_s[64][32];   // [point][x]     rows 64B aligned
  __shared__ __align__(16) ushort xz_s[64][32];   // [point][z]
  __shared__ ushort yz_t[32][66];                 // [y][point]+pad: conflict-free reads

  int l = threadIdx.x;            // lane 0..63
  int p = blockIdx.x * 64 + l;
  float c0c = coords[3 * p + 0] * (1.0f / 1.3f);
  float c1c = coords[3 * p + 1] * (1.0f / 1.3f);
  float c2c = coords[3 * p + 2] * (1.0f / 1.3f);

  {
    uint buf[16];
    auto pack = [&](int c, float v) {
      ushort h = f2bf(v);
      if (c & 1) buf[c >> 1] |= ((uint)h << 16);
      else buf[c >> 1] = (uint)h;
    };
    // xy: W<-x(c0), H<-y(c1)
    sample_plane<true>(planes_t, nullptr, c0c, c1c, pack);
    uint4* r = (uint4*)xy_s[l];
#pragma unroll
    for (int i = 0; i < 4; ++i)
      r[i] = make_uint4(buf[4*i], buf[4*i+1], buf[4*i+2], buf[4*i+3]);
    // xz: W<-x(c0), H<-z(c2)
    sample_plane<true>(planes_t + (size_t)2 * PLANE_T_ELEMS, nullptr, c0c, c2c, pack);
    r = (uint4*)xz_s[l];
#pragma unroll
    for (int i = 0; i < 4; ++i)
      r[i] = make_uint4(buf[4*i], buf[4*i+1], buf[4*i+2], buf[4*i+3]);
    // yz: W<-y(c1), H<-z(c2), stored transposed (point-contiguous rows)
    sample_plane<true>(planes_t + (size_t)PLANE_T_ELEMS, nullptr, c1c, c2c,
                       [&](int c, float v) { yz_t[c][l] = f2bf(v); });
  }
  __syncthreads();

  int s = l & 15;          // point-in-tile (A row / D col)
  int kb = l >> 4;         // k-block 0..3 (D row group)

  // preload this lane's xz values for all 4 tiles: z = kb*8 + j
  float xzf[4][8];
#pragma unroll
  for (int t = 0; t < 4; ++t) {
    uint4 xzu = ((const uint4*)xz_s[t * 16 + s])[kb];
    xzf[t][0] = bf_lo(xzu.x); xzf[t][1] = bf_hi(xzu.x);
    xzf[t][2] = bf_lo(xzu.y); xzf[t][3] = bf_hi(xzu.y);
    xzf[t][4] = bf_lo(xzu.z); xzf[t][5] = bf_hi(xzu.z);
    xzf[t][6] = bf_lo(xzu.w); xzf[t][7] = bf_hi(xzu.w);
  }

  f32x4 acc[4][2];
#pragma unroll
  for (int t = 0; t < 4; ++t) {
    acc[t][0] = (f32x4){0.f, 0.f, 0.f, 0.f};
    acc[t][1] = (f32x4){0.f, 0.f, 0.f, 0.f};
  }

  const ushort* gl = grb + (size_t)l * 8;   // lane's B-frag base
#pragma unroll
  for (int y = 0; y < 32; ++y) {
    bf16x8 b0 = *(const bf16x8*)(gl + y * 1024);        // x = 0..15  cols
    bf16x8 b1 = *(const bf16x8*)(gl + y * 1024 + 512);  // x = 16..31 cols
#pragma unroll
    for (int t = 0; t < 4; ++t) {
      float yv = b2f(yz_t[y][t * 16 + s]);
      union { uint u[4]; bf16x8 v; } a;
      a.u[0] = cvtpk_bf16(yv * xzf[t][0], yv * xzf[t][1]);
      a.u[1] = cvtpk_bf16(yv * xzf[t][2], yv * xzf[t][3]);
      a.u[2] = cvtpk_bf16(yv * xzf[t][4], yv * xzf[t][5]);
      a.u[3] = cvtpk_bf16(yv * xzf[t][6], yv * xzf[t][7]);
      acc[t][0] = __builtin_amdgcn_mfma_f32_16x16x32_bf16(a.v, b0, acc[t][0], 0, 0, 0);
      acc[t][1] = __builtin_amdgcn_mfma_f32_16x16x32_bf16(a.v, b1, acc[t][1], 0, 0, 0);
    }
  }

  // epilogue: out[m] = sum_x xy[m][x] * W[m][x]; D row=(kb*4+r)=point, col=s=x
  int gp0 = blockIdx.x * 64;
#pragma unroll
  for (int t = 0; t < 4; ++t) {
#pragma unroll
    for (int r = 0; r < 4; ++r) {
      int m = kb * 4 + r;
      int pm = t * 16 + m;
      float v = acc[t][0][r] * b2f(xy_s[pm][s]) + acc[t][1][r] * b2f(xy_s[pm][16 + s]);
      v += __shfl_xor(v, 1, 64);
      v += __shfl_xor(v, 2, 64);
      v += __shfl_xor(v, 4, 64);
      v += __shfl_xor(v, 8, 64);
      if (s == 0) out[gp0 + pm] = v;
    }
  }
}

// ---------- fallback (no workspace): slow-but-correct ----------
__global__ __launch_bounds__(256) void tucker_small_k(
    const float* __restrict__ coords,
    const float* __restrict__ pxy, const float* __restrict__ pyz,
    const float* __restrict__ pxz, const float* __restrict__ g,
    float* __restrict__ out) {
  __shared__ float s_yz[256 * 33];
  int tid = threadIdx.x;
  int p = blockIdx.x * 256 + tid;
  float c0 = coords[3 * p + 0] / 1.3f;
  float c1 = coords[3 * p + 1] / 1.3f;
  float c2 = coords[3 * p + 2] / 1.3f;
  float xy[32], xz[32];
  float* yzrow = &s_yz[tid * 33];
  sample_plane<false>(nullptr, pxy, c0, c1, [&](int c, float v) { xy[c] = v; });
  sample_plane<false>(nullptr, pyz, c1, c2, [&](int c, float v) { yzrow[c] = v; });
  sample_plane<false>(nullptr, pxz, c0, c2, [&](int c, float v) { xz[c] = v; });
  float acc = 0.0f;
  for (int y = 0; y < 32; ++y) {
    float yzv = yzrow[y];
    float accy = 0.0f;
#pragma unroll
    for (int z = 0; z < 32; ++z) {
      float t0 = 0.f, t1 = 0.f, t2 = 0.f, t3 = 0.f;
#pragma unroll
      for (int x = 0; x < 32; x += 4) {
        t0 = fmaf(g[(x + 0) * 1024 + y * 32 + z], xy[x + 0], t0);
        t1 = fmaf(g[(x + 1) * 1024 + y * 32 + z], xy[x + 1], t1);
        t2 = fmaf(g[(x + 2) * 1024 + y * 32 + z], xy[x + 2], t2);
        t3 = fmaf(g[(x + 3) * 1024 + y * 32 + z], xy[x + 3], t3);
      }
      accy = fmaf((t0 + t1) + (t2 + t3), xz[z], accy);
    }
    acc = fmaf(accy, yzv, acc);
  }
  out[p] = acc;
}

extern "C" void kernel_launch(void* const* d_in, const int* in_sizes, int n_in,
                              void* d_out, int out_size, void* d_ws, size_t ws_size,
                              hipStream_t stream) {
  const float* coords = (const float*)d_in[0];
  const float* pxy = (const float*)d_in[1];
  const float* pyz = (const float*)d_in[2];
  const float* pxz = (const float*)d_in[3];
  const float* g   = (const float*)d_in[4];
  float* out = (float*)d_out;

  if (ws_size >= WS_NEEDED) {
    ushort* planes_t = (ushort*)d_ws;
    ushort* grb = (ushort*)((char*)d_ws + WS_GRB_OFF);
    hipLaunchKernelGGL(transpose_planes_k, dim3(768), dim3(256), 0, stream,
                       pxy, pyz, pxz, planes_t);
    hipLaunchKernelGGL(prep_grb_k, dim3(128), dim3(256), 0, stream, g, grb);
    hipLaunchKernelGGL(tucker_mfma_k, dim3(NPTS / 64), dim3(64), 0, stream,
                       coords, planes_t, grb, out);
  } else {
    hipLaunchKernelGGL(tucker_small_k, dim3(NPTS / 256), dim3(256), 0, stream,
                       coords, pxy, pyz, pxz, g, out);
  }
}